// Round 2
// baseline (2965.149 us; speedup 1.0000x reference)
//
#include <hip/hip_runtime.h>
#include <cstdint>
#include <cmath>

#define B_    64
#define K_    4096
#define DIM_  50257
#define DIMP_ 50688      // 99*512, padded (pad logged to 0)
#define KNN_  8
#define NSEG_ 4
#define SEGD_ 12800      // segs 0-2: 12800 d; seg 3: 11857 d (padded to 12288)
#define SB_   512        // d-superblock
#define ROWS_ 16         // k-rows per workgroup
#define LN2_  0.6931471805599453

// ---------------- kernel A: LT[b][d] = log2(logits[b][d]), zero-padded ----
__global__ void log_kernel(const float* __restrict__ logits, float* __restrict__ LT) {
    int d = blockIdx.x * 256 + threadIdx.x;     // 0..DIMP-1
    int b = blockIdx.y;
    float v = 0.0f;
    if (d < DIM_) v = __log2f(logits[(size_t)b * DIM_ + d]);
    LT[(size_t)b * DIMP_ + d] = v;
}

// ---------------- kernel B: the big pass -----------------------------------
// grid = 1024 blocks (256 ktiles x 4 d-segments, XCD-swizzled), block = 1024.
// Block tile: 16 k-rows x 64 b-cols over one d-segment.
// 16 waves = 2 row-groups x 8 b-groups; each wave: 8 rows x 8 b, acc[8][8].
// Inner slot (256 d): 8x ds_read_b128 (A rows) + 8x dwordx4 (L) + 256 FMA.
__global__ __launch_bounds__(1024, 4) void main_kernel(
        const float* __restrict__ A, const float* __restrict__ LT,
        float* __restrict__ Spart, float* __restrict__ t1part) {
    __shared__ float As[ROWS_ * SB_];   // 32 KB

    const int t    = threadIdx.x;
    const int lane = t & 63;
    const int wv   = __builtin_amdgcn_readfirstlane(t >> 6);   // wave id 0..15 (SGPR)
    const int g    = wv >> 3;           // row-group 0/1  -> rows [g*8, g*8+8)
    const int bg   = wv & 7;            // b-group        -> cols [bg*8, bg*8+8)

    // XCD-aware swizzle: all blocks on an XCD share one d-segment -> L seg (3.2 MB) pinned in that XCD's L2
    const int wg   = blockIdx.x;        // 0..1023
    const int xcd  = wg & 7;
    const int y    = wg >> 3;           // 0..127
    const int seg  = xcd & 3;
    const int ktile = ((xcd >> 2) << 7) + y;   // 0..255, bijective
    const int kbase = ktile * ROWS_;
    const int d0    = seg * SEGD_;
    const int dend  = min(d0 + SEGD_, DIM_);

    float acc[8][8];                    // [jb][r]
#pragma unroll
    for (int jb = 0; jb < 8; ++jb)
#pragma unroll
        for (int r = 0; r < 8; ++r) acc[jb][r] = 0.0f;
    float t1a = 0.0f;

    const int srow = t >> 6;            // staging row 0..15 (== wv)
    const int sl   = t & 63;
    const float* Arow = A + (size_t)(kbase + srow) * DIM_;
    const float* LTb  = LT + (size_t)(bg * 8) * DIMP_;

    for (int ds = d0; ds < dend; ds += SB_) {
        // ---- stage A tile to LDS; a*log2(a) computed exactly once per element
#pragma unroll
        for (int j = 0; j < 8; ++j) {
            const int dl = sl + j * 64;
            const int d  = ds + dl;
            float a = 1.0f;                     // pad: 1*log2(1)=0, 1*Lpad(0)=0
            if (d < DIM_) a = Arow[d];
            t1a = fmaf(a, __log2f(a), t1a);
            As[srow * SB_ + dl] = a;
        }
        __syncthreads();

        // ---- 2 slots of 256 d
#pragma unroll
        for (int slot = 0; slot < 2; ++slot) {
            const int dl = slot * 256 + lane * 4;
            float4 av[8];
#pragma unroll
            for (int r = 0; r < 8; ++r)
                av[r] = *(const float4*)&As[(g * 8 + r) * SB_ + dl];
            const float* LTd = LTb + ds + dl;
#pragma unroll
            for (int jb = 0; jb < 8; ++jb) {
                const float4 Lv = *(const float4*)&LTd[(size_t)jb * DIMP_];
#pragma unroll
                for (int r = 0; r < 8; ++r) {
                    acc[jb][r] = fmaf(av[r].x, Lv.x, acc[jb][r]);
                    acc[jb][r] = fmaf(av[r].y, Lv.y, acc[jb][r]);
                    acc[jb][r] = fmaf(av[r].z, Lv.z, acc[jb][r]);
                    acc[jb][r] = fmaf(av[r].w, Lv.w, acc[jb][r]);
                }
            }
        }
        __syncthreads();
    }

    // ---- cross-lane reduce: 64 acc elements per wave; lane (jb*8+r) keeps its value
    float sval = 0.0f;
#pragma unroll
    for (int jb = 0; jb < 8; ++jb) {
#pragma unroll
        for (int r = 0; r < 8; ++r) {
            float v = acc[jb][r];
#pragma unroll
            for (int m = 32; m > 0; m >>= 1) v += __shfl_xor(v, m, 64);
            if (lane == (jb * 8 + r)) sval = v;
        }
    }
    {
        const int jb = lane >> 3, r = lane & 7;
        Spart[((size_t)(kbase + g * 8 + r) * 64 + (bg * 8 + jb)) * NSEG_ + seg] = sval;
    }

    // ---- t1: all 64 lanes of wave wv hold partials for row wv
    {
        float s = t1a;
#pragma unroll
        for (int m = 32; m > 0; m >>= 1) s += __shfl_xor(s, m, 64);
        if (lane == 0) t1part[(size_t)(kbase + wv) * NSEG_ + seg] = s;
    }
}

// ---------------- kernel C1: t1 segment combine (f64) ----------------------
__global__ void t1sum_kernel(const float* __restrict__ t1part, double* __restrict__ t1d) {
    int k = blockIdx.x * 256 + threadIdx.x;
    if (k < K_) {
        double s = 0.0;
        for (int j = 0; j < NSEG_; ++j) s += (double)t1part[k * NSEG_ + j];
        t1d[k] = s;
    }
}

// ---------------- kernel C2: scaled_dists[b][k] -----------------------------
__global__ void dist_kernel(const float* __restrict__ Spart, const double* __restrict__ t1d,
                            float* __restrict__ scaled) {
    int tid = blockIdx.x * 256 + threadIdx.x;   // B*K threads
    int b = tid >> 12;
    int k = tid & 4095;
    const float4 sp = *(const float4*)&Spart[((size_t)k * 64 + b) * NSEG_];
    double s = (double)sp.x + (double)sp.y + (double)sp.z + (double)sp.w;
    const double C = -(1.0 / 0.05) * LN2_ / (double)DIM_;   // fold ln2 + mean + (-1/T)
    scaled[(size_t)b * K_ + k] = (float)(C * (t1d[k] - s));
}

// ---------------- kernel D: per-row top-8 + softmax + class scatter ---------
__global__ void topk_kernel(const float* __restrict__ scaled, const int* __restrict__ label,
                            float* __restrict__ out) {
    __shared__ float vals[K_];
    __shared__ float rv[256];
    __shared__ int   ri[256];
    __shared__ float topv[KNN_];
    __shared__ int   topi[KNN_];
    const int b = blockIdx.x, t = threadIdx.x;
    for (int i = t; i < K_; i += 256) vals[i] = scaled[(size_t)b * K_ + i];
    __syncthreads();
    for (int it = 0; it < KNN_; ++it) {
        float bv = -INFINITY; int bi = K_;
        for (int i = t; i < K_; i += 256) {      // ascending: first max = lowest idx (tie rule)
            float v = vals[i];
            if (v > bv) { bv = v; bi = i; }
        }
        rv[t] = bv; ri[t] = bi;
        __syncthreads();
        for (int s = 128; s > 0; s >>= 1) {
            if (t < s) {
                float v2 = rv[t + s]; int i2 = ri[t + s];
                if (v2 > rv[t] || (v2 == rv[t] && i2 < ri[t])) { rv[t] = v2; ri[t] = i2; }
            }
            __syncthreads();
        }
        if (t == 0) { topv[it] = rv[0]; topi[it] = ri[0]; vals[ri[0]] = -INFINITY; }
        __syncthreads();
    }
    if (t == 0) {
        const float m = topv[0];
        float w[KNN_], s = 0.0f;
        for (int i = 0; i < KNN_; ++i) { w[i] = expf(topv[i] - m); s += w[i]; }
        float p0 = 0.0f, p1 = 0.0f;
        for (int i = 0; i < KNN_; ++i) {
            const float ww = w[i] / s;
            if (label[topi[i]] != 0) p1 += ww; else p0 += ww;
        }
        out[b * 2 + 0] = p0;
        out[b * 2 + 1] = p1;
    }
}

// ---------------- launch -----------------------------------------------------
extern "C" void kernel_launch(void* const* d_in, const int* in_sizes, int n_in,
                              void* d_out, int out_size, void* d_ws, size_t ws_size,
                              hipStream_t stream) {
    const float* logits = (const float*)d_in[0];
    const float* A      = (const float*)d_in[1];    // queue_anchor
    const int*   label  = (const int*)d_in[2];      // jax default x64-off -> int32
    float*       out    = (float*)d_out;

    char* ws = (char*)d_ws;
    float*  LT     = (float*)(ws);                          // 50688*64*4  = 12,976,128
    float*  Spart  = (float*)(ws + 12976128);               // 4096*64*4*4 =  4,194,304
    float*  t1part = (float*)(ws + 12976128 + 4194304);     // 4096*4*4    =     65,536
    double* t1d    = (double*)(ws + 12976128 + 4194304 + 65536);          //     32,768
    float*  scaled = (float*)(ws + 12976128 + 4194304 + 65536 + 32768);   //  1,048,576

    dim3 gA(DIMP_ / 256, B_);
    log_kernel<<<gA, 256, 0, stream>>>(logits, LT);

    main_kernel<<<1024, 1024, 0, stream>>>(A, LT, Spart, t1part);

    t1sum_kernel<<<K_ / 256, 256, 0, stream>>>(t1part, t1d);

    dist_kernel<<<(B_ * K_) / 256, 256, 0, stream>>>(Spart, t1d, scaled);

    topk_kernel<<<B_, 256, 0, stream>>>(scaled, label, out);
}

// Round 3
// 1838.272 us; speedup vs baseline: 1.6130x; 1.6130x over previous
//
#include <hip/hip_runtime.h>
#include <cstdint>
#include <cmath>

#define B_    64
#define K_    4096
#define DIM_  50257
#define DLAST 50256              // last column: scalar tail (x4 loads would run past A's end)
#define DIMP_ 51200              // padded D for LT3 (multiple of 4*SLD alignment)
#define KNN_  8
#define NSL_  16                 // d-slices
#define SLD_  3200               // d per slice (NSL_*SLD_ = DIMP_)
#define LN2_  0.6931471805599453

typedef float f32x4 __attribute__((ext_vector_type(4)));

// ---------- kernel A: LT3[d>>2][b][d&3] = log2(logits[b][d]), zero-padded ----
// Layout lets lane b read 4 consecutive d's as one aligned dwordx4.
__global__ void log_kernel(const float* __restrict__ logits, float* __restrict__ LT3) {
    int d = blockIdx.x * 256 + threadIdx.x;     // 0..DIMP_-1
    int b = blockIdx.y;
    float v = 0.0f;
    if (d < DIM_) v = __log2f(logits[(size_t)b * DIM_ + d]);
    LT3[(size_t)(d >> 2) * 256 + b * 4 + (d & 3)] = v;
}

// ---------- kernel B: the big pass ------------------------------------------
// lanes = b (wave covers all 64 batch cols). Wave owns 16 k-rows x one d-slice.
// Per 4-d chunk: 1 dwordx4 L-load (per-lane), 16 uniform broadcast x4 A-loads,
// 1 per-lane A-gather for t1, 64 FMAs. No LDS, no barriers, no lane reduce
// for acc (acc[r] IS the (k,b) slice-partial). Block = 4 waves = 4 k-tiles
// sharing one d-slice (L rides L1/L2; slice pinned per XCD).
__global__ __launch_bounds__(256) void main_kernel(
        const float* __restrict__ A, const float* __restrict__ LT3,
        float* __restrict__ Spart, float* __restrict__ t1part) {
    const int t    = threadIdx.x;
    const int lane = t & 63;
    const int wv   = t >> 6;

    const int bid = blockIdx.x;         // 0..1023
    const int xcd = bid & 7;
    const int idx = bid >> 3;           // 0..127
    const int sl  = (xcd << 1) | (idx & 1);   // 0..15, pinned per XCD
    const int ktg = idx >> 1;           // 0..63
    const int kbase = __builtin_amdgcn_readfirstlane((ktg * 4 + wv) * 16);

    const int d0    = sl * SLD_;
    const int dmain = min(d0 + SLD_, DLAST);

    const float* Ar0 = A + (size_t)kbase * DIM_;
    const float* Ag  = A + (size_t)(kbase + (lane >> 2)) * DIM_ + (lane & 3);

    float acc[16];
#pragma unroll
    for (int r = 0; r < 16; ++r) acc[r] = 0.0f;
    float t1a = 0.0f;

    for (int d = d0; d < dmain; d += 4) {
        f32x4 Lv;
        __builtin_memcpy(&Lv, &LT3[(size_t)(d >> 2) * 256 + lane * 4], 16);
        const float tg = Ag[d];                       // per-lane gather (rides L1)
        t1a = fmaf(tg, __log2f(tg), t1a);
#pragma unroll
        for (int r = 0; r < 16; ++r) {
            f32x4 av;                                 // wave-uniform broadcast load
            __builtin_memcpy(&av, Ar0 + (size_t)r * DIM_ + d, 16);
            acc[r] = fmaf(av.x, Lv.x, acc[r]);
            acc[r] = fmaf(av.y, Lv.y, acc[r]);
            acc[r] = fmaf(av.z, Lv.z, acc[r]);
            acc[r] = fmaf(av.w, Lv.w, acc[r]);
        }
    }

    // t1: lane l held (row = l>>2, d%4 = l&3) partials; sum over the quad
    float t1s = t1a + __shfl_xor(t1a, 1, 64);
    t1s = t1s + __shfl_xor(t1s, 2, 64);

    // scalar tail: column d = 50256 (only the last slice owns it)
    if (sl == NSL_ - 1) {
        const float Lcol = LT3[(size_t)(DLAST >> 2) * 256 + lane * 4];
#pragma unroll
        for (int r = 0; r < 16; ++r) {
            const float ac = Ar0[(size_t)r * DIM_ + DLAST];   // in-bounds (<= last element)
            acc[r] = fmaf(ac, Lcol, acc[r]);
            if (lane == (r << 2)) t1s = fmaf(ac, __log2f(ac), t1s);
        }
    }

    // stores: fully coalesced 256B per row
#pragma unroll
    for (int r = 0; r < 16; ++r)
        Spart[((size_t)sl * K_ + kbase + r) * 64 + lane] = acc[r];
    if ((lane & 3) == 0)
        t1part[(size_t)(kbase + (lane >> 2)) * NSL_ + sl] = t1s;
}

// ---------- kernel C1: t1 slice combine (f64) -------------------------------
__global__ void t1sum_kernel(const float* __restrict__ t1part, double* __restrict__ t1d) {
    int k = blockIdx.x * 256 + threadIdx.x;
    if (k < K_) {
        double s = 0.0;
        for (int j = 0; j < NSL_; ++j) s += (double)t1part[k * NSL_ + j];
        t1d[k] = s;
    }
}

// ---------- kernel C2: scaled_dists[b][k] ------------------------------------
__global__ void dist_kernel(const float* __restrict__ Spart, const double* __restrict__ t1d,
                            float* __restrict__ scaled) {
    int tid = blockIdx.x * 256 + threadIdx.x;   // B*K threads
    int b = tid & 63;                            // b fast -> coalesced Spart reads
    int k = tid >> 6;
    double s = 0.0;
    for (int j = 0; j < NSL_; ++j)
        s += (double)Spart[((size_t)j * K_ + k) * 64 + b];
    const double C = -(1.0 / 0.05) * LN2_ / (double)DIM_;   // fold ln2 + mean + (-1/T)
    scaled[(size_t)b * K_ + k] = (float)(C * (t1d[k] - s));
}

// ---------- kernel D: per-row top-8 + softmax + class scatter ----------------
__global__ void topk_kernel(const float* __restrict__ scaled, const int* __restrict__ label,
                            float* __restrict__ out) {
    __shared__ float vals[K_];
    __shared__ float rv[256];
    __shared__ int   ri[256];
    __shared__ float topv[KNN_];
    __shared__ int   topi[KNN_];
    const int b = blockIdx.x, t = threadIdx.x;
    for (int i = t; i < K_; i += 256) vals[i] = scaled[(size_t)b * K_ + i];
    __syncthreads();
    for (int it = 0; it < KNN_; ++it) {
        float bv = -INFINITY; int bi = K_;
        for (int i = t; i < K_; i += 256) {      // ascending: first max = lowest idx (tie rule)
            float v = vals[i];
            if (v > bv) { bv = v; bi = i; }
        }
        rv[t] = bv; ri[t] = bi;
        __syncthreads();
        for (int s = 128; s > 0; s >>= 1) {
            if (t < s) {
                float v2 = rv[t + s]; int i2 = ri[t + s];
                if (v2 > rv[t] || (v2 == rv[t] && i2 < ri[t])) { rv[t] = v2; ri[t] = i2; }
            }
            __syncthreads();
        }
        if (t == 0) { topv[it] = rv[0]; topi[it] = ri[0]; vals[ri[0]] = -INFINITY; }
        __syncthreads();
    }
    if (t == 0) {
        const float m = topv[0];
        float w[KNN_], s = 0.0f;
        for (int i = 0; i < KNN_; ++i) { w[i] = expf(topv[i] - m); s += w[i]; }
        float p0 = 0.0f, p1 = 0.0f;
        for (int i = 0; i < KNN_; ++i) {
            const float ww = w[i] / s;
            if (label[topi[i]] != 0) p1 += ww; else p0 += ww;
        }
        out[b * 2 + 0] = p0;
        out[b * 2 + 1] = p1;
    }
}

// ---------- launch ------------------------------------------------------------
extern "C" void kernel_launch(void* const* d_in, const int* in_sizes, int n_in,
                              void* d_out, int out_size, void* d_ws, size_t ws_size,
                              hipStream_t stream) {
    const float* logits = (const float*)d_in[0];
    const float* A      = (const float*)d_in[1];    // queue_anchor
    const int*   label  = (const int*)d_in[2];      // jax x64-off -> int32
    float*       out    = (float*)d_out;

    char* ws = (char*)d_ws;
    float*  LT3    = (float*)(ws);                               // 51200/4*256*4 = 13,107,200
    float*  Spart  = (float*)(ws + 13107200);                    // 16*4096*64*4  = 16,777,216
    float*  t1part = (float*)(ws + 13107200 + 16777216);         // 4096*16*4     =    262,144
    double* t1d    = (double*)(ws + 13107200 + 16777216 + 262144);            //      32,768
    float*  scaled = (float*)(ws + 13107200 + 16777216 + 262144 + 32768);     //   1,048,576
    // total ~31.2 MB

    dim3 gA(DIMP_ / 256, B_);
    log_kernel<<<gA, 256, 0, stream>>>(logits, LT3);

    main_kernel<<<1024, 256, 0, stream>>>(A, LT3, Spart, t1part);

    t1sum_kernel<<<K_ / 256, 256, 0, stream>>>(t1part, t1d);

    dist_kernel<<<(B_ * K_) / 256, 256, 0, stream>>>(Spart, t1d, scaled);

    topk_kernel<<<B_, 256, 0, stream>>>(scaled, label, out);
}